// Round 8
// baseline (1270.590 us; speedup 1.0000x reference)
//
#include <hip/hip_runtime.h>

#define KF 128
#define NSUP 256
#define NSPEC 4
#define GRID 2048     // 256-thread blocks, grid-stride
#define BLOCK 256

typedef __bf16 bf16x8 __attribute__((ext_vector_type(8)));
typedef float  f32x4  __attribute__((ext_vector_type(4)));

// ---------------- build per-species Gram matrix, fragment-major bf16 ----------------
// G[s][c][k] = sum_m w[s][m]*sup[s][m][c]*sup[s][m][k]  (fp32 accum -> bf16)
// Fragment-major: t = ((s*8+ct)*4+kk)*64+lane holds 8 bf16:
//   G[s][ct*16+(lane&15)][kk*32+(lane>>4)*8 + j]   (A-operand of 16x16x32 MFMA)

__global__ void k_buildG(const float* __restrict__ sup, const float* __restrict__ w,
                         __bf16* __restrict__ gfrag) {
    const int t = blockIdx.x * blockDim.x + threadIdx.x;   // 8192 threads
    if (t >= NSPEC * 8 * 4 * 64) return;
    const int lane = t & 63;
    const int kk   = (t >> 6) & 3;
    const int ct   = (t >> 8) & 7;
    const int s    = t >> 11;
    const int c  = ct * 16 + (lane & 15);
    const int k0 = kk * 32 + (lane >> 4) * 8;
    const float* S = sup + (size_t)s * NSUP * KF;
    const float* W = w + s * NSUP;
    float acc0 = 0.f, acc1 = 0.f, acc2 = 0.f, acc3 = 0.f;
    float acc4 = 0.f, acc5 = 0.f, acc6 = 0.f, acc7 = 0.f;
    for (int m = 0; m < NSUP; ++m) {
        const float wc = W[m] * S[m * KF + c];
        const float4 ka = *(const float4*)(S + m * KF + k0);
        const float4 kb = *(const float4*)(S + m * KF + k0 + 4);
        acc0 += wc * ka.x; acc1 += wc * ka.y; acc2 += wc * ka.z; acc3 += wc * ka.w;
        acc4 += wc * kb.x; acc5 += wc * kb.y; acc6 += wc * kb.z; acc7 += wc * kb.w;
    }
    bf16x8 o;
    o[0] = (__bf16)acc0; o[1] = (__bf16)acc1; o[2] = (__bf16)acc2; o[3] = (__bf16)acc3;
    o[4] = (__bf16)acc4; o[5] = (__bf16)acc5; o[6] = (__bf16)acc6; o[7] = (__bf16)acc7;
    *(bf16x8*)(gfrag + (size_t)t * 8) = o;
}

// ---------------- register-only helpers ----------------

__device__ __forceinline__ int4 cvt8(const float* p, bool v, float& nacc) {
    float4 A = v ? *(const float4*)p : make_float4(0.f, 0.f, 0.f, 0.f);
    float4 B = v ? *(const float4*)(p + 4) : make_float4(0.f, 0.f, 0.f, 0.f);
    nacc += A.x * A.x + A.y * A.y + A.z * A.z + A.w * A.w
          + B.x * B.x + B.y * B.y + B.z * B.z + B.w * B.w;
    bf16x8 o;
    o[0] = (__bf16)A.x; o[1] = (__bf16)A.y; o[2] = (__bf16)A.z; o[3] = (__bf16)A.w;
    o[4] = (__bf16)B.x; o[5] = (__bf16)B.y; o[6] = (__bf16)B.z; o[7] = (__bf16)B.w;
    return __builtin_bit_cast(int4, o);
}

// One ct-step: shuffle-extract x in C-layout, 4 species x 4 kk MFMA for both
// atom-sets (G-fragment read once, feeds 2 MFMAs), species-predicated pairing.
template<int CT>
__device__ __forceinline__ void ct_step(
    int4 fA0, int4 fA1, int4 fA2, int4 fA3,
    int4 fB0, int4 fB1, int4 fB2, int4 fB3,
    const __bf16* __restrict__ gfrag, int lane, int r, int g,
    int spcA, int spcB, float& eA, float& eB)
{
    constexpr int KP = CT >> 1;
    const int4 sA = (KP == 0) ? fA0 : (KP == 1) ? fA1 : (KP == 2) ? fA2 : fA3;
    const int4 sB = (KP == 0) ? fB0 : (KP == 1) ? fB1 : (KP == 2) ? fB2 : fB3;

    const int srcl = (((CT & 1) * 2 + (g >> 1)) << 4) | r;
    int a0 = __shfl(sA.x, srcl), a1 = __shfl(sA.y, srcl),
        a2 = __shfl(sA.z, srcl), a3 = __shfl(sA.w, srcl);
    int b0 = __shfl(sB.x, srcl), b1 = __shfl(sB.y, srcl),
        b2 = __shfl(sB.z, srcl), b3 = __shfl(sB.w, srcl);
    const int loA = (g & 1) ? a2 : a0, hiA = (g & 1) ? a3 : a1;
    const int loB = (g & 1) ? b2 : b0, hiB = (g & 1) ? b3 : b1;
    const float xa0 = __int_as_float(loA << 16);
    const float xa1 = __int_as_float(loA & 0xffff0000);
    const float xa2 = __int_as_float(hiA << 16);
    const float xa3 = __int_as_float(hiA & 0xffff0000);
    const float xb0 = __int_as_float(loB << 16);
    const float xb1 = __int_as_float(loB & 0xffff0000);
    const float xb2 = __int_as_float(hiB << 16);
    const float xb3 = __int_as_float(hiB & 0xffff0000);

    #pragma unroll
    for (int s = 0; s < NSPEC; ++s) {
        const __bf16* gp = gfrag + ((size_t)(((s << 3) | CT) << 2) << 6) * 8 + (size_t)lane * 8;
        f32x4 aA = (f32x4){0.f, 0.f, 0.f, 0.f};
        f32x4 aB = (f32x4){0.f, 0.f, 0.f, 0.f};
        {
            bf16x8 Gf = *(const bf16x8*)(gp);
            aA = __builtin_amdgcn_mfma_f32_16x16x32_bf16(Gf, __builtin_bit_cast(bf16x8, fA0), aA, 0, 0, 0);
            aB = __builtin_amdgcn_mfma_f32_16x16x32_bf16(Gf, __builtin_bit_cast(bf16x8, fB0), aB, 0, 0, 0);
        }
        {
            bf16x8 Gf = *(const bf16x8*)(gp + 512);
            aA = __builtin_amdgcn_mfma_f32_16x16x32_bf16(Gf, __builtin_bit_cast(bf16x8, fA1), aA, 0, 0, 0);
            aB = __builtin_amdgcn_mfma_f32_16x16x32_bf16(Gf, __builtin_bit_cast(bf16x8, fB1), aB, 0, 0, 0);
        }
        {
            bf16x8 Gf = *(const bf16x8*)(gp + 1024);
            aA = __builtin_amdgcn_mfma_f32_16x16x32_bf16(Gf, __builtin_bit_cast(bf16x8, fA2), aA, 0, 0, 0);
            aB = __builtin_amdgcn_mfma_f32_16x16x32_bf16(Gf, __builtin_bit_cast(bf16x8, fB2), aB, 0, 0, 0);
        }
        {
            bf16x8 Gf = *(const bf16x8*)(gp + 1536);
            aA = __builtin_amdgcn_mfma_f32_16x16x32_bf16(Gf, __builtin_bit_cast(bf16x8, fA3), aA, 0, 0, 0);
            aB = __builtin_amdgcn_mfma_f32_16x16x32_bf16(Gf, __builtin_bit_cast(bf16x8, fB3), aB, 0, 0, 0);
        }
        float dA = xa0 * aA[0] + xa1 * aA[1] + xa2 * aA[2] + xa3 * aA[3];
        float dB = xb0 * aB[0] + xb1 * aB[1] + xb2 * aB[2] + xb3 * aB[3];
        if (spcA == s) eA += dA;
        if (spcB == s) eB += dB;
    }
}

// ---------------- main kernel: sequential stream, no LDS, no barriers ----------------

__global__ __launch_bounds__(BLOCK, 4) void k_main(
    const float* __restrict__ ps,
    const __bf16* __restrict__ gfrag,
    const int* __restrict__ species,
    const int* __restrict__ sids,
    float* __restrict__ out,
    int n)
{
    const int lane = threadIdx.x & 63;
    const int r = lane & 15, g = lane >> 4;
    const int wid = blockIdx.x * (BLOCK / 64) + (threadIdx.x >> 6);
    const int gs = GRID * (BLOCK / 64);
    const int ntiles = (n + 31) / 32;

    for (int t = wid; t < ntiles; t += gs) {
        const int base = t * 32;

        int aA = base + r,      aB = base + 16 + r;
        bool vA = aA < n,       vB = aB < n;
        int rA = vA ? aA : 0,   rB = vB ? aB : 0;
        int spcA = vA ? species[rA] : -1;
        int spcB = vB ? species[rB] : -1;
        int sidA = vA ? sids[rA] : 0;
        int sidB = vB ? sids[rB] : 0;

        const float* pA = ps + (size_t)rA * KF + g * 8;
        const float* pB = ps + (size_t)rB * KF + g * 8;
        float nA = 0.f, nB = 0.f;
        int4 fA0 = cvt8(pA +  0, vA, nA);
        int4 fA1 = cvt8(pA + 32, vA, nA);
        int4 fA2 = cvt8(pA + 64, vA, nA);
        int4 fA3 = cvt8(pA + 96, vA, nA);
        int4 fB0 = cvt8(pB +  0, vB, nB);
        int4 fB1 = cvt8(pB + 32, vB, nB);
        int4 fB2 = cvt8(pB + 64, vB, nB);
        int4 fB3 = cvt8(pB + 96, vB, nB);
        nA += __shfl_xor(nA, 16); nA += __shfl_xor(nA, 32);
        nB += __shfl_xor(nB, 16); nB += __shfl_xor(nB, 32);

        float eA = 0.f, eB = 0.f;
        ct_step<0>(fA0,fA1,fA2,fA3, fB0,fB1,fB2,fB3, gfrag, lane, r, g, spcA, spcB, eA, eB);
        ct_step<1>(fA0,fA1,fA2,fA3, fB0,fB1,fB2,fB3, gfrag, lane, r, g, spcA, spcB, eA, eB);
        ct_step<2>(fA0,fA1,fA2,fA3, fB0,fB1,fB2,fB3, gfrag, lane, r, g, spcA, spcB, eA, eB);
        ct_step<3>(fA0,fA1,fA2,fA3, fB0,fB1,fB2,fB3, gfrag, lane, r, g, spcA, spcB, eA, eB);
        ct_step<4>(fA0,fA1,fA2,fA3, fB0,fB1,fB2,fB3, gfrag, lane, r, g, spcA, spcB, eA, eB);
        ct_step<5>(fA0,fA1,fA2,fA3, fB0,fB1,fB2,fB3, gfrag, lane, r, g, spcA, spcB, eA, eB);
        ct_step<6>(fA0,fA1,fA2,fA3, fB0,fB1,fB2,fB3, gfrag, lane, r, g, spcA, spcB, eA, eB);
        ct_step<7>(fA0,fA1,fA2,fA3, fB0,fB1,fB2,fB3, gfrag, lane, r, g, spcA, spcB, eA, eB);

        float uA = (nA > 0.f) ? eA / nA : 0.f;
        float uB = (nB > 0.f) ? eB / nB : 0.f;

        int s0 = __shfl(sidA, 0);
        bool uni = __all(sidA == s0) && __all(sidB == s0);
        if (uni) {
            float tot = uA + uB;
            tot += __shfl_xor(tot, 1);  tot += __shfl_xor(tot, 2);
            tot += __shfl_xor(tot, 4);  tot += __shfl_xor(tot, 8);
            tot += __shfl_xor(tot, 16); tot += __shfl_xor(tot, 32);
            if (lane == 0 && tot != 0.f) atomicAdd(&out[s0], tot);
        } else {
            uA += __shfl_xor(uA, 16); uA += __shfl_xor(uA, 32);
            uB += __shfl_xor(uB, 16); uB += __shfl_xor(uB, 32);
            if (g == 0) {
                if (vA) atomicAdd(&out[sidA], uA);
                if (vB) atomicAdd(&out[sidB], uB);
            }
        }
    }
}

// ---------------- slow-but-correct fallback (ws too small) ----------------

__global__ void k_fallback(const float* __restrict__ ps, const float* __restrict__ support,
                           const float* __restrict__ weights, const int* __restrict__ species,
                           const int* __restrict__ struct_ids, float* __restrict__ out, int n)
{
    int gw = (blockIdx.x * blockDim.x + threadIdx.x) >> 6;
    int lane = threadIdx.x & 63;
    int nw = (gridDim.x * blockDim.x) >> 6;
    for (int atom = gw; atom < n; atom += nw) {
        const float* row = ps + (size_t)atom * KF;
        float x0 = row[lane], x1 = row[lane + 64];
        float nsum = x0 * x0 + x1 * x1;
        for (int o = 32; o; o >>= 1) nsum += __shfl_xor(nsum, o);
        float iv2 = 1.0f / nsum;
        int s = species[atom];
        const float* sup = support + (size_t)s * NSUP * KF;
        const float* w = weights + (size_t)s * NSUP;
        float e = 0.f;
        for (int mm = 0; mm < 4; ++mm) {
            int m = lane + mm * 64;
            const float* srow = sup + (size_t)m * KF;
            float d = 0.f;
            for (int k = 0; k < KF; ++k) d += row[k] * srow[k];
            e += d * d * w[m];
        }
        for (int o = 32; o; o >>= 1) e += __shfl_xor(e, o);
        if (lane == 0) atomicAdd(&out[struct_ids[atom]], e * iv2);
    }
}

// ---------------- launch ----------------

extern "C" void kernel_launch(void* const* d_in, const int* in_sizes, int n_in,
                              void* d_out, int out_size, void* d_ws, size_t ws_size,
                              hipStream_t stream)
{
    const float* ps       = (const float*)d_in[0];
    const float* support  = (const float*)d_in[1];
    const float* weights  = (const float*)d_in[2];
    const int*   species  = (const int*)d_in[3];
    const int*   sids     = (const int*)d_in[4];
    float* out = (float*)d_out;
    const int n = in_sizes[0] / KF;

    hipMemsetAsync(d_out, 0, (size_t)out_size * sizeof(float), stream);

    const size_t gbytes = (size_t)NSPEC * 8 * 4 * 64 * 8 * sizeof(__bf16);   // 128 KB
    if (ws_size < gbytes) {
        k_fallback<<<2048, 256, 0, stream>>>(ps, support, weights, species, sids, out, n);
        return;
    }

    __bf16* gfrag = (__bf16*)d_ws;
    k_buildG<<<(NSPEC * 8 * 4 * 64 + 255) / 256, 256, 0, stream>>>(support, weights, gfrag);
    k_main<<<GRID, BLOCK, 0, stream>>>(ps, gfrag, species, sids, out, n);
}

// Round 9
// 919.659 us; speedup vs baseline: 1.3816x; 1.3816x over previous
//
#include <hip/hip_runtime.h>

#define KF 128
#define NSUP 256
#define NSPEC 4
#define GRID 2048
#define BLOCK 256

typedef __bf16 bf16x8 __attribute__((ext_vector_type(8)));
typedef float  f32x4  __attribute__((ext_vector_type(4)));

// ---------------- build per-species Gram matrix, fragment-major bf16 ----------------
// G[s][c][k] = sum_m w[s][m]*sup[s][m][c]*sup[s][m][k]  (fp32 accum -> bf16)
// t = ((s*8+ct)*4+kk)*64+lane holds 8 bf16: G[s][ct*16+(lane&15)][kk*32+(lane>>4)*8+j]

__global__ void k_buildG(const float* __restrict__ sup, const float* __restrict__ w,
                         __bf16* __restrict__ gfrag) {
    const int t = blockIdx.x * blockDim.x + threadIdx.x;
    if (t >= NSPEC * 8 * 4 * 64) return;
    const int lane = t & 63;
    const int kk   = (t >> 6) & 3;
    const int ct   = (t >> 8) & 7;
    const int s    = t >> 11;
    const int c  = ct * 16 + (lane & 15);
    const int k0 = kk * 32 + (lane >> 4) * 8;
    const float* S = sup + (size_t)s * NSUP * KF;
    const float* W = w + s * NSUP;
    float a0 = 0.f, a1 = 0.f, a2 = 0.f, a3 = 0.f, a4 = 0.f, a5 = 0.f, a6 = 0.f, a7 = 0.f;
    for (int m = 0; m < NSUP; ++m) {
        const float wc = W[m] * S[m * KF + c];
        const float4 ka = *(const float4*)(S + m * KF + k0);
        const float4 kb = *(const float4*)(S + m * KF + k0 + 4);
        a0 += wc * ka.x; a1 += wc * ka.y; a2 += wc * ka.z; a3 += wc * ka.w;
        a4 += wc * kb.x; a5 += wc * kb.y; a6 += wc * kb.z; a7 += wc * kb.w;
    }
    bf16x8 o;
    o[0] = (__bf16)a0; o[1] = (__bf16)a1; o[2] = (__bf16)a2; o[3] = (__bf16)a3;
    o[4] = (__bf16)a4; o[5] = (__bf16)a5; o[6] = (__bf16)a6; o[7] = (__bf16)a7;
    *(bf16x8*)(gfrag + (size_t)t * 8) = o;
}

// ---------------- main kernel: sequential stream, r5-shape, Gram form ----------------
// Per 16-atom wave-tile: z = G_s x via MFMA (A = G fragment from L2-resident gfrag,
// B = atom fragment in regs). acc lane(g,r) reg j = z[atom r][16ct+4g+j].
// Pair with fp32 x shuffled to the same layout; species-predicated; /||x||^2.

// One ct-step. PL/PH are the float4s holding x[r][32*(CT>>1) + 8g .. +7].
#define CT_STEP(CT, PL, PH)                                                        \
    {                                                                              \
        const int srcl = ((((CT) & 1) * 2 + (g >> 1)) << 4) | r;                   \
        float q0x = __shfl(PL.x, srcl), q0y = __shfl(PL.y, srcl),                  \
              q0z = __shfl(PL.z, srcl), q0w = __shfl(PL.w, srcl);                  \
        float q1x = __shfl(PH.x, srcl), q1y = __shfl(PH.y, srcl),                  \
              q1z = __shfl(PH.z, srcl), q1w = __shfl(PH.w, srcl);                  \
        const float xc0 = (g & 1) ? q1x : q0x;                                     \
        const float xc1 = (g & 1) ? q1y : q0y;                                     \
        const float xc2 = (g & 1) ? q1z : q0z;                                     \
        const float xc3 = (g & 1) ? q1w : q0w;                                     \
        _Pragma("unroll")                                                          \
        for (int s = 0; s < NSPEC; ++s) {                                          \
            const __bf16* gp = gfrag + (size_t)((s * 8 + (CT)) * 2048) + lane * 8; \
            f32x4 acc = (f32x4){0.f, 0.f, 0.f, 0.f};                               \
            acc = __builtin_amdgcn_mfma_f32_16x16x32_bf16(                         \
                *(const bf16x8*)(gp), xf0, acc, 0, 0, 0);                          \
            acc = __builtin_amdgcn_mfma_f32_16x16x32_bf16(                         \
                *(const bf16x8*)(gp + 512), xf1, acc, 0, 0, 0);                    \
            acc = __builtin_amdgcn_mfma_f32_16x16x32_bf16(                         \
                *(const bf16x8*)(gp + 1024), xf2, acc, 0, 0, 0);                   \
            acc = __builtin_amdgcn_mfma_f32_16x16x32_bf16(                         \
                *(const bf16x8*)(gp + 1536), xf3, acc, 0, 0, 0);                   \
            float d = xc0 * acc[0] + xc1 * acc[1] + xc2 * acc[2] + xc3 * acc[3];   \
            e += (spc == s) ? d : 0.f;                                             \
        }                                                                          \
    }

__device__ __forceinline__ bf16x8 pack8(float4 a, float4 b) {
    bf16x8 o;
    o[0] = (__bf16)a.x; o[1] = (__bf16)a.y; o[2] = (__bf16)a.z; o[3] = (__bf16)a.w;
    o[4] = (__bf16)b.x; o[5] = (__bf16)b.y; o[6] = (__bf16)b.z; o[7] = (__bf16)b.w;
    return o;
}

__global__ __launch_bounds__(BLOCK, 2) void k_main(
    const float* __restrict__ ps,
    const __bf16* __restrict__ gfrag,
    const int* __restrict__ species,
    const int* __restrict__ sids,
    float* __restrict__ out,
    int n)
{
    const int lane = threadIdx.x & 63;
    const int r = lane & 15, g = lane >> 4;
    const int wid = blockIdx.x * (BLOCK / 64) + (threadIdx.x >> 6);
    const int gs = GRID * (BLOCK / 64);
    const int ntiles = (n + 15) / 16;

    for (int t = wid; t < ntiles; t += gs) {
        const int a = t * 16 + r;
        const bool v = a < n;
        const int ra = v ? a : 0;
        const int spc = v ? species[ra] : -1;
        const int sid = v ? sids[ra] : 0;

        const float* p = ps + (size_t)ra * KF + g * 8;
        const float4 z4 = make_float4(0.f, 0.f, 0.f, 0.f);
        float4 p0 = v ? *(const float4*)(p +  0) : z4;
        float4 p1 = v ? *(const float4*)(p +  4) : z4;
        float4 p2 = v ? *(const float4*)(p + 32) : z4;
        float4 p3 = v ? *(const float4*)(p + 36) : z4;
        float4 p4 = v ? *(const float4*)(p + 64) : z4;
        float4 p5 = v ? *(const float4*)(p + 68) : z4;
        float4 p6 = v ? *(const float4*)(p + 96) : z4;
        float4 p7 = v ? *(const float4*)(p + 100) : z4;

        float nn = p0.x*p0.x + p0.y*p0.y + p0.z*p0.z + p0.w*p0.w
                 + p1.x*p1.x + p1.y*p1.y + p1.z*p1.z + p1.w*p1.w
                 + p2.x*p2.x + p2.y*p2.y + p2.z*p2.z + p2.w*p2.w
                 + p3.x*p3.x + p3.y*p3.y + p3.z*p3.z + p3.w*p3.w
                 + p4.x*p4.x + p4.y*p4.y + p4.z*p4.z + p4.w*p4.w
                 + p5.x*p5.x + p5.y*p5.y + p5.z*p5.z + p5.w*p5.w
                 + p6.x*p6.x + p6.y*p6.y + p6.z*p6.z + p6.w*p6.w
                 + p7.x*p7.x + p7.y*p7.y + p7.z*p7.z + p7.w*p7.w;
        nn += __shfl_xor(nn, 16);
        nn += __shfl_xor(nn, 32);

        const bf16x8 xf0 = pack8(p0, p1);
        const bf16x8 xf1 = pack8(p2, p3);
        const bf16x8 xf2 = pack8(p4, p5);
        const bf16x8 xf3 = pack8(p6, p7);

        float e = 0.f;
        CT_STEP(0, p0, p1)
        CT_STEP(1, p0, p1)
        CT_STEP(2, p2, p3)
        CT_STEP(3, p2, p3)
        CT_STEP(4, p4, p5)
        CT_STEP(5, p4, p5)
        CT_STEP(6, p6, p7)
        CT_STEP(7, p6, p7)

        float u = (nn > 0.f) ? e / nn : 0.f;   // g-slice partial of atom r's energy

        const int s0 = __shfl(sid, 0);
        const bool uni = __all(sid == s0);
        if (uni) {
            float tot = u;
            tot += __shfl_xor(tot, 1);  tot += __shfl_xor(tot, 2);
            tot += __shfl_xor(tot, 4);  tot += __shfl_xor(tot, 8);
            tot += __shfl_xor(tot, 16); tot += __shfl_xor(tot, 32);
            if (lane == 0 && tot != 0.f) atomicAdd(&out[s0], tot);
        } else {
            u += __shfl_xor(u, 16);
            u += __shfl_xor(u, 32);
            if (g == 0 && v) atomicAdd(&out[sid], u);
        }
    }
}

// ---------------- slow-but-correct fallback (ws too small) ----------------

__global__ void k_fallback(const float* __restrict__ ps, const float* __restrict__ support,
                           const float* __restrict__ weights, const int* __restrict__ species,
                           const int* __restrict__ struct_ids, float* __restrict__ out, int n)
{
    int gw = (blockIdx.x * blockDim.x + threadIdx.x) >> 6;
    int lane = threadIdx.x & 63;
    int nw = (gridDim.x * blockDim.x) >> 6;
    for (int atom = gw; atom < n; atom += nw) {
        const float* row = ps + (size_t)atom * KF;
        float x0 = row[lane], x1 = row[lane + 64];
        float nsum = x0 * x0 + x1 * x1;
        for (int o = 32; o; o >>= 1) nsum += __shfl_xor(nsum, o);
        float iv2 = 1.0f / nsum;
        int s = species[atom];
        const float* sup = support + (size_t)s * NSUP * KF;
        const float* w = weights + (size_t)s * NSUP;
        float e = 0.f;
        for (int mm = 0; mm < 4; ++mm) {
            int m = lane + mm * 64;
            const float* srow = sup + (size_t)m * KF;
            float d = 0.f;
            for (int k = 0; k < KF; ++k) d += row[k] * srow[k];
            e += d * d * w[m];
        }
        for (int o = 32; o; o >>= 1) e += __shfl_xor(e, o);
        if (lane == 0) atomicAdd(&out[struct_ids[atom]], e * iv2);
    }
}

// ---------------- launch ----------------

extern "C" void kernel_launch(void* const* d_in, const int* in_sizes, int n_in,
                              void* d_out, int out_size, void* d_ws, size_t ws_size,
                              hipStream_t stream)
{
    const float* ps       = (const float*)d_in[0];
    const float* support  = (const float*)d_in[1];
    const float* weights  = (const float*)d_in[2];
    const int*   species  = (const int*)d_in[3];
    const int*   sids     = (const int*)d_in[4];
    float* out = (float*)d_out;
    const int n = in_sizes[0] / KF;

    hipMemsetAsync(d_out, 0, (size_t)out_size * sizeof(float), stream);

    const size_t gbytes = (size_t)NSPEC * 8 * 4 * 64 * 8 * sizeof(__bf16);   // 128 KB
    if (ws_size < gbytes) {
        k_fallback<<<2048, 256, 0, stream>>>(ps, support, weights, species, sids, out, n);
        return;
    }

    __bf16* gfrag = (__bf16*)d_ws;
    k_buildG<<<(NSPEC * 8 * 4 * 64 + 255) / 256, 256, 0, stream>>>(support, weights, gfrag);
    k_main<<<GRID, BLOCK, 0, stream>>>(ps, gfrag, species, sids, out, n);
}

// Round 10
// 295.546 us; speedup vs baseline: 4.2991x; 3.1117x over previous
//
#include <hip/hip_runtime.h>

#define KF 128
#define NSUP 256
#define NSPEC 4
#define GRID 2048
#define BLOCK 256

typedef __bf16 bf16x8 __attribute__((ext_vector_type(8)));
typedef float  f32x4  __attribute__((ext_vector_type(4)));

// ---------------- build per-species Gram matrix, sigma-permuted fragment-major ----------------
// G[s][c][k] = sum_m w[s][m]*sup[s][m][c]*sup[s][m][k]  (fp32 accum -> bf16)
// Stored as MFMA A-fragments for 16x16x32: t = ((s*8+ct)*4+kk)*64+lane holds
//   G[s][ sigma(ct, lane&15) ][ kk*32 + (lane>>4)*8 + u ],  u=0..7
// sigma(ct,i) = (ct>>1)*32 + (i>>2)*8 + (ct&1)*4 + (i&3)  -- chosen so that the
// MFMA D-layout places z[sigma] on the lane that already holds x[sigma] (no shuffles).

__global__ void k_buildG(const float* __restrict__ sup, const float* __restrict__ w,
                         __bf16* __restrict__ gfrag) {
    const int t = blockIdx.x * blockDim.x + threadIdx.x;   // 8192 total
    if (t >= NSPEC * 8 * 4 * 64) return;
    const int lane = t & 63;
    const int kk   = (t >> 6) & 3;
    const int ct   = (t >> 8) & 7;
    const int s    = t >> 11;
    const int i    = lane & 15;
    const int c    = (ct >> 1) * 32 + (i >> 2) * 8 + (ct & 1) * 4 + (i & 3);
    const int k0   = kk * 32 + (lane >> 4) * 8;
    const float* S = sup + (size_t)s * NSUP * KF;
    const float* W = w + s * NSUP;
    float a0 = 0.f, a1 = 0.f, a2 = 0.f, a3 = 0.f, a4 = 0.f, a5 = 0.f, a6 = 0.f, a7 = 0.f;
    for (int m = 0; m < NSUP; ++m) {
        const float wc = W[m] * S[m * KF + c];
        const float4 ka = *(const float4*)(S + m * KF + k0);
        const float4 kb = *(const float4*)(S + m * KF + k0 + 4);
        a0 += wc * ka.x; a1 += wc * ka.y; a2 += wc * ka.z; a3 += wc * ka.w;
        a4 += wc * kb.x; a5 += wc * kb.y; a6 += wc * kb.z; a7 += wc * kb.w;
    }
    bf16x8 o;
    o[0] = (__bf16)a0; o[1] = (__bf16)a1; o[2] = (__bf16)a2; o[3] = (__bf16)a3;
    o[4] = (__bf16)a4; o[5] = (__bf16)a5; o[6] = (__bf16)a6; o[7] = (__bf16)a7;
    *(bf16x8*)(gfrag + (size_t)t * 8) = o;
}

// ---------------- main kernel ----------------
// Per 16-atom wave-tile, per species: z = G_s x via 8 ct-steps x 4 kk MFMA.
// acc[j] (ct) = z[sigma(ct,4g+j)][atom r]  pairs directly with p_ct[j] (own lane).
// e = sum over own c-slice, species-predicated; reduce over g-lanes; /||x||^2.

// One ct-step. P = float4 holding x[sigma(ct, 4g + 0..3)] = p_ct.
#define GSTEP(CT, P)                                                            \
    {                                                                           \
        const __bf16* gq = gp + (CT) * 2048;                                    \
        f32x4 acc = (f32x4){0.f, 0.f, 0.f, 0.f};                                \
        acc = __builtin_amdgcn_mfma_f32_16x16x32_bf16(                          \
            *(const bf16x8*)(gq), xf0, acc, 0, 0, 0);                           \
        acc = __builtin_amdgcn_mfma_f32_16x16x32_bf16(                          \
            *(const bf16x8*)(gq + 512), xf1, acc, 0, 0, 0);                     \
        acc = __builtin_amdgcn_mfma_f32_16x16x32_bf16(                          \
            *(const bf16x8*)(gq + 1024), xf2, acc, 0, 0, 0);                    \
        acc = __builtin_amdgcn_mfma_f32_16x16x32_bf16(                          \
            *(const bf16x8*)(gq + 1536), xf3, acc, 0, 0, 0);                    \
        es += acc[0] * P.x + acc[1] * P.y + acc[2] * P.z + acc[3] * P.w;        \
    }

__device__ __forceinline__ bf16x8 pack8(float4 a, float4 b) {
    bf16x8 o;
    o[0] = (__bf16)a.x; o[1] = (__bf16)a.y; o[2] = (__bf16)a.z; o[3] = (__bf16)a.w;
    o[4] = (__bf16)b.x; o[5] = (__bf16)b.y; o[6] = (__bf16)b.z; o[7] = (__bf16)b.w;
    return o;
}

__global__ __launch_bounds__(BLOCK, 4) void k_main(
    const float* __restrict__ ps,
    const __bf16* __restrict__ gfrag,
    const int* __restrict__ species,
    const int* __restrict__ sids,
    float* __restrict__ out,
    int n)
{
    const int lane = threadIdx.x & 63;
    const int r = lane & 15, g = lane >> 4;
    const int wid = blockIdx.x * (BLOCK / 64) + (threadIdx.x >> 6);
    const int gs = GRID * (BLOCK / 64);
    const int ntiles = (n + 15) / 16;

    for (int t = wid; t < ntiles; t += gs) {
        const int a = t * 16 + r;
        const bool v = a < n;
        const int ra = v ? a : 0;
        const int spc = v ? species[ra] : -1;
        const int sid = v ? sids[ra] : 0;

        const float* p = ps + (size_t)ra * KF + g * 8;
        const float4 z4 = make_float4(0.f, 0.f, 0.f, 0.f);
        float4 p0 = v ? *(const float4*)(p +  0) : z4;
        float4 p1 = v ? *(const float4*)(p +  4) : z4;
        float4 p2 = v ? *(const float4*)(p + 32) : z4;
        float4 p3 = v ? *(const float4*)(p + 36) : z4;
        float4 p4 = v ? *(const float4*)(p + 64) : z4;
        float4 p5 = v ? *(const float4*)(p + 68) : z4;
        float4 p6 = v ? *(const float4*)(p + 96) : z4;
        float4 p7 = v ? *(const float4*)(p + 100) : z4;

        float nn = p0.x*p0.x + p0.y*p0.y + p0.z*p0.z + p0.w*p0.w
                 + p1.x*p1.x + p1.y*p1.y + p1.z*p1.z + p1.w*p1.w
                 + p2.x*p2.x + p2.y*p2.y + p2.z*p2.z + p2.w*p2.w
                 + p3.x*p3.x + p3.y*p3.y + p3.z*p3.z + p3.w*p3.w
                 + p4.x*p4.x + p4.y*p4.y + p4.z*p4.z + p4.w*p4.w
                 + p5.x*p5.x + p5.y*p5.y + p5.z*p5.z + p5.w*p5.w
                 + p6.x*p6.x + p6.y*p6.y + p6.z*p6.z + p6.w*p6.w
                 + p7.x*p7.x + p7.y*p7.y + p7.z*p7.z + p7.w*p7.w;
        nn += __shfl_xor(nn, 16);
        nn += __shfl_xor(nn, 32);

        const bf16x8 xf0 = pack8(p0, p1);
        const bf16x8 xf1 = pack8(p2, p3);
        const bf16x8 xf2 = pack8(p4, p5);
        const bf16x8 xf3 = pack8(p6, p7);

        float e = 0.f;
        #pragma unroll 1
        for (int s = 0; s < NSPEC; ++s) {
            const __bf16* gp = gfrag + (size_t)s * 16384 + (size_t)lane * 8;
            float es = 0.f;
            GSTEP(0, p0)
            GSTEP(1, p1)
            __builtin_amdgcn_sched_barrier(0);
            GSTEP(2, p2)
            GSTEP(3, p3)
            __builtin_amdgcn_sched_barrier(0);
            GSTEP(4, p4)
            GSTEP(5, p5)
            __builtin_amdgcn_sched_barrier(0);
            GSTEP(6, p6)
            GSTEP(7, p7)
            e += (spc == s) ? es : 0.f;
        }

        // per-lane g-slice partial of atom r's energy
        float u = (nn > 0.f) ? e / nn : 0.f;

        const int s0 = __shfl(sid, 0);
        const bool uni = __all(sid == s0);
        if (uni) {
            float tot = u;   // sum of ALL lanes' partials = sum of atom energies
            tot += __shfl_xor(tot, 1);  tot += __shfl_xor(tot, 2);
            tot += __shfl_xor(tot, 4);  tot += __shfl_xor(tot, 8);
            tot += __shfl_xor(tot, 16); tot += __shfl_xor(tot, 32);
            if (lane == 0 && tot != 0.f) atomicAdd(&out[s0], tot);
        } else {
            u += __shfl_xor(u, 16);
            u += __shfl_xor(u, 32);
            if (g == 0 && v) atomicAdd(&out[sid], u);
        }
    }
}

// ---------------- slow-but-correct fallback (ws too small) ----------------

__global__ void k_fallback(const float* __restrict__ ps, const float* __restrict__ support,
                           const float* __restrict__ weights, const int* __restrict__ species,
                           const int* __restrict__ struct_ids, float* __restrict__ out, int n)
{
    int gw = (blockIdx.x * blockDim.x + threadIdx.x) >> 6;
    int lane = threadIdx.x & 63;
    int nw = (gridDim.x * blockDim.x) >> 6;
    for (int atom = gw; atom < n; atom += nw) {
        const float* row = ps + (size_t)atom * KF;
        float x0 = row[lane], x1 = row[lane + 64];
        float nsum = x0 * x0 + x1 * x1;
        for (int o = 32; o; o >>= 1) nsum += __shfl_xor(nsum, o);
        float iv2 = 1.0f / nsum;
        int s = species[atom];
        const float* sup = support + (size_t)s * NSUP * KF;
        const float* w = weights + (size_t)s * NSUP;
        float e = 0.f;
        for (int mm = 0; mm < 4; ++mm) {
            int m = lane + mm * 64;
            const float* srow = sup + (size_t)m * KF;
            float d = 0.f;
            for (int k = 0; k < KF; ++k) d += row[k] * srow[k];
            e += d * d * w[m];
        }
        for (int o = 32; o; o >>= 1) e += __shfl_xor(e, o);
        if (lane == 0) atomicAdd(&out[struct_ids[atom]], e * iv2);
    }
}

// ---------------- launch ----------------

extern "C" void kernel_launch(void* const* d_in, const int* in_sizes, int n_in,
                              void* d_out, int out_size, void* d_ws, size_t ws_size,
                              hipStream_t stream)
{
    const float* ps       = (const float*)d_in[0];
    const float* support  = (const float*)d_in[1];
    const float* weights  = (const float*)d_in[2];
    const int*   species  = (const int*)d_in[3];
    const int*   sids     = (const int*)d_in[4];
    float* out = (float*)d_out;
    const int n = in_sizes[0] / KF;

    hipMemsetAsync(d_out, 0, (size_t)out_size * sizeof(float), stream);

    const size_t gbytes = (size_t)NSPEC * 8 * 4 * 64 * 8 * sizeof(__bf16);   // 128 KB
    if (ws_size < gbytes) {
        k_fallback<<<2048, 256, 0, stream>>>(ps, support, weights, species, sids, out, n);
        return;
    }

    __bf16* gfrag = (__bf16*)d_ws;
    k_buildG<<<(NSPEC * 8 * 4 * 64 + 255) / 256, 256, 0, stream>>>(support, weights, gfrag);
    k_main<<<GRID, BLOCK, 0, stream>>>(ps, gfrag, species, sids, out, n);
}

// Round 11
// 188.878 us; speedup vs baseline: 6.7270x; 1.5647x over previous
//
#include <hip/hip_runtime.h>

#define KF 128
#define NSUP 256
#define NSPEC 4
#define GRID 256      // 1 block per CU (LDS-capped)
#define BLOCK 512     // 8 waves

typedef __bf16 bf16x8 __attribute__((ext_vector_type(8)));
typedef float  f32x4  __attribute__((ext_vector_type(4)));

// ---------------- build per-species Gram matrix, sigma-permuted fragment-major ----------------
// G[s][c][k] = sum_m w[s][m]*sup[s][m][c]*sup[s][m][k]  (fp32 accum -> bf16)
// t = ((s*8+ct)*4+kk)*64+lane holds G[s][sigma(ct,lane&15)][kk*32+(lane>>4)*8+u], u=0..7
// sigma(ct,i) = (ct>>1)*32 + (i>>2)*8 + (ct&1)*4 + (i&3): MFMA D-layout lands z[c] on
// the lane that already holds x[c] -> pairing needs no cross-lane moves.

__global__ void k_buildG(const float* __restrict__ sup, const float* __restrict__ w,
                         __bf16* __restrict__ gfrag) {
    const int t = blockIdx.x * blockDim.x + threadIdx.x;   // 8192 total
    if (t >= NSPEC * 8 * 4 * 64) return;
    const int lane = t & 63;
    const int kk   = (t >> 6) & 3;
    const int ct   = (t >> 8) & 7;
    const int s    = t >> 11;
    const int i    = lane & 15;
    const int c    = (ct >> 1) * 32 + (i >> 2) * 8 + (ct & 1) * 4 + (i & 3);
    const int k0   = kk * 32 + (lane >> 4) * 8;
    const float* S = sup + (size_t)s * NSUP * KF;
    const float* W = w + s * NSUP;
    float a0 = 0.f, a1 = 0.f, a2 = 0.f, a3 = 0.f, a4 = 0.f, a5 = 0.f, a6 = 0.f, a7 = 0.f;
    for (int m = 0; m < NSUP; ++m) {
        const float wc = W[m] * S[m * KF + c];
        const float4 ka = *(const float4*)(S + m * KF + k0);
        const float4 kb = *(const float4*)(S + m * KF + k0 + 4);
        a0 += wc * ka.x; a1 += wc * ka.y; a2 += wc * ka.z; a3 += wc * ka.w;
        a4 += wc * kb.x; a5 += wc * kb.y; a6 += wc * kb.z; a7 += wc * kb.w;
    }
    bf16x8 o;
    o[0] = (__bf16)a0; o[1] = (__bf16)a1; o[2] = (__bf16)a2; o[3] = (__bf16)a3;
    o[4] = (__bf16)a4; o[5] = (__bf16)a5; o[6] = (__bf16)a6; o[7] = (__bf16)a7;
    *(bf16x8*)(gfrag + (size_t)t * 8) = o;
}

// ---------------- main kernel: G in LDS, sequential ps stream, 1-ahead prefetch ----------------

// One ct-step: 4 chained MFMA (A = G fragment from LDS), pair acc[j] with own-lane
// x values unpacked from the bf16 fragment XF (elements (CT&1)*4 .. +3).
#define GSTEP(CT, XF)                                                           \
    {                                                                           \
        const __bf16* gq = gp + (CT) * 2048;                                    \
        f32x4 acc = (f32x4){0.f, 0.f, 0.f, 0.f};                                \
        acc = __builtin_amdgcn_mfma_f32_16x16x32_bf16(                          \
            *(const bf16x8*)(gq), xf0, acc, 0, 0, 0);                           \
        acc = __builtin_amdgcn_mfma_f32_16x16x32_bf16(                          \
            *(const bf16x8*)(gq + 512), xf1, acc, 0, 0, 0);                     \
        acc = __builtin_amdgcn_mfma_f32_16x16x32_bf16(                          \
            *(const bf16x8*)(gq + 1024), xf2, acc, 0, 0, 0);                    \
        acc = __builtin_amdgcn_mfma_f32_16x16x32_bf16(                          \
            *(const bf16x8*)(gq + 1536), xf3, acc, 0, 0, 0);                    \
        es += acc[0] * (float)XF[((CT) & 1) * 4 + 0]                            \
            + acc[1] * (float)XF[((CT) & 1) * 4 + 1]                            \
            + acc[2] * (float)XF[((CT) & 1) * 4 + 2]                            \
            + acc[3] * (float)XF[((CT) & 1) * 4 + 3];                           \
    }

__device__ __forceinline__ bf16x8 pack8(float4 a, float4 b) {
    bf16x8 o;
    o[0] = (__bf16)a.x; o[1] = (__bf16)a.y; o[2] = (__bf16)a.z; o[3] = (__bf16)a.w;
    o[4] = (__bf16)b.x; o[5] = (__bf16)b.y; o[6] = (__bf16)b.z; o[7] = (__bf16)b.w;
    return o;
}

__global__ __launch_bounds__(BLOCK, 1) void k_main(
    const float* __restrict__ ps,
    const __bf16* __restrict__ gfrag,
    const int* __restrict__ species,
    const int* __restrict__ sids,
    float* __restrict__ out,
    int n)
{
    __shared__ __align__(16) __bf16 Glds[NSPEC * 128 * 128];   // 128 KB

    for (int f = threadIdx.x; f < 8192; f += BLOCK)
        ((int4*)Glds)[f] = ((const int4*)gfrag)[f];
    __syncthreads();

    const int lane = threadIdx.x & 63;
    const int r = lane & 15, g = lane >> 4;
    const int wid = blockIdx.x * (BLOCK / 64) + (threadIdx.x >> 6);
    const int gs = GRID * (BLOCK / 64);
    const int ntiles = (n + 15) / 16;

    int t = wid;
    if (t >= ntiles) return;

    const float4 z4 = make_float4(0.f, 0.f, 0.f, 0.f);

    // ---- prologue: load tile t ----
    int a = t * 16 + r;
    bool v = a < n;
    int ra = v ? a : 0;
    int spc = v ? species[ra] : -1;
    int sid = v ? sids[ra] : 0;
    const float* p = ps + (size_t)ra * KF + g * 8;
    float4 pf0 = v ? *(const float4*)(p +   0) : z4;
    float4 pf1 = v ? *(const float4*)(p +   4) : z4;
    float4 pf2 = v ? *(const float4*)(p +  32) : z4;
    float4 pf3 = v ? *(const float4*)(p +  36) : z4;
    float4 pf4 = v ? *(const float4*)(p +  64) : z4;
    float4 pf5 = v ? *(const float4*)(p +  68) : z4;
    float4 pf6 = v ? *(const float4*)(p +  96) : z4;
    float4 pf7 = v ? *(const float4*)(p + 100) : z4;

    for (; t < ntiles; t += gs) {
        const int spc_c = spc, sid_c = sid;
        const bool v_c = v;

        // ---- norms (fp32) ----
        float nn = pf0.x*pf0.x + pf0.y*pf0.y + pf0.z*pf0.z + pf0.w*pf0.w
                 + pf1.x*pf1.x + pf1.y*pf1.y + pf1.z*pf1.z + pf1.w*pf1.w
                 + pf2.x*pf2.x + pf2.y*pf2.y + pf2.z*pf2.z + pf2.w*pf2.w
                 + pf3.x*pf3.x + pf3.y*pf3.y + pf3.z*pf3.z + pf3.w*pf3.w
                 + pf4.x*pf4.x + pf4.y*pf4.y + pf4.z*pf4.z + pf4.w*pf4.w
                 + pf5.x*pf5.x + pf5.y*pf5.y + pf5.z*pf5.z + pf5.w*pf5.w
                 + pf6.x*pf6.x + pf6.y*pf6.y + pf6.z*pf6.z + pf6.w*pf6.w
                 + pf7.x*pf7.x + pf7.y*pf7.y + pf7.z*pf7.z + pf7.w*pf7.w;
        nn += __shfl_xor(nn, 16);
        nn += __shfl_xor(nn, 32);

        // ---- pack bf16 fragments ----
        const bf16x8 xf0 = pack8(pf0, pf1);
        const bf16x8 xf1 = pack8(pf2, pf3);
        const bf16x8 xf2 = pack8(pf4, pf5);
        const bf16x8 xf3 = pack8(pf6, pf7);

        // ---- prefetch next tile into pf (in flight under compute) ----
        const int tn = t + gs;
        if (tn < ntiles) {
            int a2 = tn * 16 + r;
            v = a2 < n;
            int ra2 = v ? a2 : 0;
            spc = v ? species[ra2] : -1;
            sid = v ? sids[ra2] : 0;
            const float* p2 = ps + (size_t)ra2 * KF + g * 8;
            pf0 = v ? *(const float4*)(p2 +   0) : z4;
            pf1 = v ? *(const float4*)(p2 +   4) : z4;
            pf2 = v ? *(const float4*)(p2 +  32) : z4;
            pf3 = v ? *(const float4*)(p2 +  36) : z4;
            pf4 = v ? *(const float4*)(p2 +  64) : z4;
            pf5 = v ? *(const float4*)(p2 +  68) : z4;
            pf6 = v ? *(const float4*)(p2 +  96) : z4;
            pf7 = v ? *(const float4*)(p2 + 100) : z4;
        }

        // ---- compute from LDS ----
        float e = 0.f;
        #pragma unroll 1
        for (int s = 0; s < NSPEC; ++s) {
            const __bf16* gp = Glds + s * 16384 + lane * 8;
            float es = 0.f;
            GSTEP(0, xf0)
            GSTEP(1, xf0)
            __builtin_amdgcn_sched_barrier(0);
            GSTEP(2, xf1)
            GSTEP(3, xf1)
            __builtin_amdgcn_sched_barrier(0);
            GSTEP(4, xf2)
            GSTEP(5, xf2)
            __builtin_amdgcn_sched_barrier(0);
            GSTEP(6, xf3)
            GSTEP(7, xf3)
            e += (spc_c == s) ? es : 0.f;
        }

        float u = (nn > 0.f) ? e / nn : 0.f;   // g-slice partial of atom r's energy

        const int s0 = __shfl(sid_c, 0);
        const bool uni = __all(sid_c == s0);
        if (uni) {
            float tot = u;
            tot += __shfl_xor(tot, 1);  tot += __shfl_xor(tot, 2);
            tot += __shfl_xor(tot, 4);  tot += __shfl_xor(tot, 8);
            tot += __shfl_xor(tot, 16); tot += __shfl_xor(tot, 32);
            if (lane == 0 && tot != 0.f) atomicAdd(&out[s0], tot);
        } else {
            u += __shfl_xor(u, 16);
            u += __shfl_xor(u, 32);
            if (g == 0 && v_c) atomicAdd(&out[sid_c], u);
        }
    }
}

// ---------------- slow-but-correct fallback (ws too small) ----------------

__global__ void k_fallback(const float* __restrict__ ps, const float* __restrict__ support,
                           const float* __restrict__ weights, const int* __restrict__ species,
                           const int* __restrict__ struct_ids, float* __restrict__ out, int n)
{
    int gw = (blockIdx.x * blockDim.x + threadIdx.x) >> 6;
    int lane = threadIdx.x & 63;
    int nw = (gridDim.x * blockDim.x) >> 6;
    for (int atom = gw; atom < n; atom += nw) {
        const float* row = ps + (size_t)atom * KF;
        float x0 = row[lane], x1 = row[lane + 64];
        float nsum = x0 * x0 + x1 * x1;
        for (int o = 32; o; o >>= 1) nsum += __shfl_xor(nsum, o);
        float iv2 = 1.0f / nsum;
        int s = species[atom];
        const float* sup = support + (size_t)s * NSUP * KF;
        const float* w = weights + (size_t)s * NSUP;
        float e = 0.f;
        for (int mm = 0; mm < 4; ++mm) {
            int m = lane + mm * 64;
            const float* srow = sup + (size_t)m * KF;
            float d = 0.f;
            for (int k = 0; k < KF; ++k) d += row[k] * srow[k];
            e += d * d * w[m];
        }
        for (int o = 32; o; o >>= 1) e += __shfl_xor(e, o);
        if (lane == 0) atomicAdd(&out[struct_ids[atom]], e * iv2);
    }
}

// ---------------- launch ----------------

extern "C" void kernel_launch(void* const* d_in, const int* in_sizes, int n_in,
                              void* d_out, int out_size, void* d_ws, size_t ws_size,
                              hipStream_t stream)
{
    const float* ps       = (const float*)d_in[0];
    const float* support  = (const float*)d_in[1];
    const float* weights  = (const float*)d_in[2];
    const int*   species  = (const int*)d_in[3];
    const int*   sids     = (const int*)d_in[4];
    float* out = (float*)d_out;
    const int n = in_sizes[0] / KF;

    hipMemsetAsync(d_out, 0, (size_t)out_size * sizeof(float), stream);

    const size_t gbytes = (size_t)NSPEC * 8 * 4 * 64 * 8 * sizeof(__bf16);   // 128 KB
    if (ws_size < gbytes) {
        k_fallback<<<2048, 256, 0, stream>>>(ps, support, weights, species, sids, out, n);
        return;
    }

    __bf16* gfrag = (__bf16*)d_ws;
    k_buildG<<<(NSPEC * 8 * 4 * 64 + 255) / 256, 256, 0, stream>>>(support, weights, gfrag);
    k_main<<<GRID, BLOCK, 0, stream>>>(ps, gfrag, species, sids, out, n);
}

// Round 12
// 178.712 us; speedup vs baseline: 7.1097x; 1.0569x over previous
//
#include <hip/hip_runtime.h>

#define KF 128
#define NSUP 256
#define NSPEC 4
#define GRID 256      // 1 block per CU (LDS-capped)
#define BLOCK 1024    // 16 waves -> 4 waves/SIMD

typedef __bf16 bf16x8 __attribute__((ext_vector_type(8)));
typedef float  f32x4  __attribute__((ext_vector_type(4)));

// ---------------- build per-species Gram matrix, sigma-permuted fragment-major ----------------
// G[s][c][k] = sum_m w[s][m]*sup[s][m][c]*sup[s][m][k]  (fp32 accum -> bf16)
// t = ((s*8+ct)*4+kk)*64+lane holds G[s][sigma(ct,lane&15)][kk*32+(lane>>4)*8+u], u=0..7
// sigma(ct,i) = (ct>>1)*32 + (i>>2)*8 + (ct&1)*4 + (i&3): MFMA D-layout lands z[c] on
// the lane that already holds x[c] -> pairing needs no cross-lane moves.

__global__ void k_buildG(const float* __restrict__ sup, const float* __restrict__ w,
                         __bf16* __restrict__ gfrag) {
    const int t = blockIdx.x * blockDim.x + threadIdx.x;   // 8192 total
    if (t >= NSPEC * 8 * 4 * 64) return;
    const int lane = t & 63;
    const int kk   = (t >> 6) & 3;
    const int ct   = (t >> 8) & 7;
    const int s    = t >> 11;
    const int i    = lane & 15;
    const int c    = (ct >> 1) * 32 + (i >> 2) * 8 + (ct & 1) * 4 + (i & 3);
    const int k0   = kk * 32 + (lane >> 4) * 8;
    const float* S = sup + (size_t)s * NSUP * KF;
    const float* W = w + s * NSUP;
    float a0 = 0.f, a1 = 0.f, a2 = 0.f, a3 = 0.f, a4 = 0.f, a5 = 0.f, a6 = 0.f, a7 = 0.f;
    for (int m = 0; m < NSUP; ++m) {
        const float wc = W[m] * S[m * KF + c];
        const float4 ka = *(const float4*)(S + m * KF + k0);
        const float4 kb = *(const float4*)(S + m * KF + k0 + 4);
        a0 += wc * ka.x; a1 += wc * ka.y; a2 += wc * ka.z; a3 += wc * ka.w;
        a4 += wc * kb.x; a5 += wc * kb.y; a6 += wc * kb.z; a7 += wc * kb.w;
    }
    bf16x8 o;
    o[0] = (__bf16)a0; o[1] = (__bf16)a1; o[2] = (__bf16)a2; o[3] = (__bf16)a3;
    o[4] = (__bf16)a4; o[5] = (__bf16)a5; o[6] = (__bf16)a6; o[7] = (__bf16)a7;
    *(bf16x8*)(gfrag + (size_t)t * 8) = o;
}

// ---------------- main kernel: G in LDS, sequential ps stream, 1-ahead prefetch ----------------

// One ct-step: 4 chained MFMA (A = G fragment from LDS), pair acc[j] with own-lane
// x values unpacked from the bf16 fragment XF (elements (CT&1)*4 .. +3).
#define GSTEP(CT, XF)                                                           \
    {                                                                           \
        const __bf16* gq = gp + (CT) * 2048;                                    \
        f32x4 acc = (f32x4){0.f, 0.f, 0.f, 0.f};                                \
        acc = __builtin_amdgcn_mfma_f32_16x16x32_bf16(                          \
            *(const bf16x8*)(gq), xf0, acc, 0, 0, 0);                           \
        acc = __builtin_amdgcn_mfma_f32_16x16x32_bf16(                          \
            *(const bf16x8*)(gq + 512), xf1, acc, 0, 0, 0);                     \
        acc = __builtin_amdgcn_mfma_f32_16x16x32_bf16(                          \
            *(const bf16x8*)(gq + 1024), xf2, acc, 0, 0, 0);                    \
        acc = __builtin_amdgcn_mfma_f32_16x16x32_bf16(                          \
            *(const bf16x8*)(gq + 1536), xf3, acc, 0, 0, 0);                    \
        es += acc[0] * (float)XF[((CT) & 1) * 4 + 0]                            \
            + acc[1] * (float)XF[((CT) & 1) * 4 + 1]                            \
            + acc[2] * (float)XF[((CT) & 1) * 4 + 2]                            \
            + acc[3] * (float)XF[((CT) & 1) * 4 + 3];                           \
    }

__device__ __forceinline__ bf16x8 pack8(float4 a, float4 b) {
    bf16x8 o;
    o[0] = (__bf16)a.x; o[1] = (__bf16)a.y; o[2] = (__bf16)a.z; o[3] = (__bf16)a.w;
    o[4] = (__bf16)b.x; o[5] = (__bf16)b.y; o[6] = (__bf16)b.z; o[7] = (__bf16)b.w;
    return o;
}

__global__ __launch_bounds__(BLOCK, 4) void k_main(
    const float* __restrict__ ps,
    const __bf16* __restrict__ gfrag,
    const int* __restrict__ species,
    const int* __restrict__ sids,
    float* __restrict__ out,
    int n)
{
    __shared__ __align__(16) __bf16 Glds[NSPEC * 128 * 128];   // 128 KB

    for (int f = threadIdx.x; f < 8192; f += BLOCK)
        ((int4*)Glds)[f] = ((const int4*)gfrag)[f];
    __syncthreads();

    const int lane = threadIdx.x & 63;
    const int r = lane & 15, g = lane >> 4;
    const int wid = blockIdx.x * (BLOCK / 64) + (threadIdx.x >> 6);
    const int gs = GRID * (BLOCK / 64);
    const int ntiles = (n + 15) / 16;

    int t = wid;
    if (t >= ntiles) return;

    const float4 z4 = make_float4(0.f, 0.f, 0.f, 0.f);

    // ---- prologue: load tile t ----
    int a = t * 16 + r;
    bool v = a < n;
    int ra = v ? a : 0;
    int spc = v ? species[ra] : -1;
    int sid = v ? sids[ra] : 0;
    const float* p = ps + (size_t)ra * KF + g * 8;
    float4 pf0 = v ? *(const float4*)(p +   0) : z4;
    float4 pf1 = v ? *(const float4*)(p +   4) : z4;
    float4 pf2 = v ? *(const float4*)(p +  32) : z4;
    float4 pf3 = v ? *(const float4*)(p +  36) : z4;
    float4 pf4 = v ? *(const float4*)(p +  64) : z4;
    float4 pf5 = v ? *(const float4*)(p +  68) : z4;
    float4 pf6 = v ? *(const float4*)(p +  96) : z4;
    float4 pf7 = v ? *(const float4*)(p + 100) : z4;

    for (; t < ntiles; t += gs) {
        const int spc_c = spc, sid_c = sid;
        const bool v_c = v;

        // ---- norms (fp32) ----
        float nn = pf0.x*pf0.x + pf0.y*pf0.y + pf0.z*pf0.z + pf0.w*pf0.w
                 + pf1.x*pf1.x + pf1.y*pf1.y + pf1.z*pf1.z + pf1.w*pf1.w
                 + pf2.x*pf2.x + pf2.y*pf2.y + pf2.z*pf2.z + pf2.w*pf2.w
                 + pf3.x*pf3.x + pf3.y*pf3.y + pf3.z*pf3.z + pf3.w*pf3.w
                 + pf4.x*pf4.x + pf4.y*pf4.y + pf4.z*pf4.z + pf4.w*pf4.w
                 + pf5.x*pf5.x + pf5.y*pf5.y + pf5.z*pf5.z + pf5.w*pf5.w
                 + pf6.x*pf6.x + pf6.y*pf6.y + pf6.z*pf6.z + pf6.w*pf6.w
                 + pf7.x*pf7.x + pf7.y*pf7.y + pf7.z*pf7.z + pf7.w*pf7.w;
        nn += __shfl_xor(nn, 16);
        nn += __shfl_xor(nn, 32);

        // ---- pack bf16 fragments ----
        const bf16x8 xf0 = pack8(pf0, pf1);
        const bf16x8 xf1 = pack8(pf2, pf3);
        const bf16x8 xf2 = pack8(pf4, pf5);
        const bf16x8 xf3 = pack8(pf6, pf7);

        // ---- prefetch next tile into pf (in flight under compute) ----
        const int tn = t + gs;
        if (tn < ntiles) {
            int a2 = tn * 16 + r;
            v = a2 < n;
            int ra2 = v ? a2 : 0;
            spc = v ? species[ra2] : -1;
            sid = v ? sids[ra2] : 0;
            const float* p2 = ps + (size_t)ra2 * KF + g * 8;
            pf0 = v ? *(const float4*)(p2 +   0) : z4;
            pf1 = v ? *(const float4*)(p2 +   4) : z4;
            pf2 = v ? *(const float4*)(p2 +  32) : z4;
            pf3 = v ? *(const float4*)(p2 +  36) : z4;
            pf4 = v ? *(const float4*)(p2 +  64) : z4;
            pf5 = v ? *(const float4*)(p2 +  68) : z4;
            pf6 = v ? *(const float4*)(p2 +  96) : z4;
            pf7 = v ? *(const float4*)(p2 + 100) : z4;
        }

        // ---- compute from LDS ----
        float e = 0.f;
        #pragma unroll 1
        for (int s = 0; s < NSPEC; ++s) {
            const __bf16* gp = Glds + s * 16384 + lane * 8;
            float es = 0.f;
            GSTEP(0, xf0)
            GSTEP(1, xf0)
            __builtin_amdgcn_sched_barrier(0);
            GSTEP(2, xf1)
            GSTEP(3, xf1)
            __builtin_amdgcn_sched_barrier(0);
            GSTEP(4, xf2)
            GSTEP(5, xf2)
            __builtin_amdgcn_sched_barrier(0);
            GSTEP(6, xf3)
            GSTEP(7, xf3)
            e += (spc_c == s) ? es : 0.f;
        }

        float u = (nn > 0.f) ? e / nn : 0.f;   // g-slice partial of atom r's energy

        const int s0 = __shfl(sid_c, 0);
        const bool uni = __all(sid_c == s0);
        if (uni) {
            float tot = u;
            tot += __shfl_xor(tot, 1);  tot += __shfl_xor(tot, 2);
            tot += __shfl_xor(tot, 4);  tot += __shfl_xor(tot, 8);
            tot += __shfl_xor(tot, 16); tot += __shfl_xor(tot, 32);
            if (lane == 0 && tot != 0.f) atomicAdd(&out[s0], tot);
        } else {
            u += __shfl_xor(u, 16);
            u += __shfl_xor(u, 32);
            if (g == 0 && v_c) atomicAdd(&out[sid_c], u);
        }
    }
}

// ---------------- slow-but-correct fallback (ws too small) ----------------

__global__ void k_fallback(const float* __restrict__ ps, const float* __restrict__ support,
                           const float* __restrict__ weights, const int* __restrict__ species,
                           const int* __restrict__ struct_ids, float* __restrict__ out, int n)
{
    int gw = (blockIdx.x * blockDim.x + threadIdx.x) >> 6;
    int lane = threadIdx.x & 63;
    int nw = (gridDim.x * blockDim.x) >> 6;
    for (int atom = gw; atom < n; atom += nw) {
        const float* row = ps + (size_t)atom * KF;
        float x0 = row[lane], x1 = row[lane + 64];
        float nsum = x0 * x0 + x1 * x1;
        for (int o = 32; o; o >>= 1) nsum += __shfl_xor(nsum, o);
        float iv2 = 1.0f / nsum;
        int s = species[atom];
        const float* sup = support + (size_t)s * NSUP * KF;
        const float* w = weights + (size_t)s * NSUP;
        float e = 0.f;
        for (int mm = 0; mm < 4; ++mm) {
            int m = lane + mm * 64;
            const float* srow = sup + (size_t)m * KF;
            float d = 0.f;
            for (int k = 0; k < KF; ++k) d += row[k] * srow[k];
            e += d * d * w[m];
        }
        for (int o = 32; o; o >>= 1) e += __shfl_xor(e, o);
        if (lane == 0) atomicAdd(&out[struct_ids[atom]], e * iv2);
    }
}

// ---------------- launch ----------------

extern "C" void kernel_launch(void* const* d_in, const int* in_sizes, int n_in,
                              void* d_out, int out_size, void* d_ws, size_t ws_size,
                              hipStream_t stream)
{
    const float* ps       = (const float*)d_in[0];
    const float* support  = (const float*)d_in[1];
    const float* weights  = (const float*)d_in[2];
    const int*   species  = (const int*)d_in[3];
    const int*   sids     = (const int*)d_in[4];
    float* out = (float*)d_out;
    const int n = in_sizes[0] / KF;

    hipMemsetAsync(d_out, 0, (size_t)out_size * sizeof(float), stream);

    const size_t gbytes = (size_t)NSPEC * 8 * 4 * 64 * 8 * sizeof(__bf16);   // 128 KB
    if (ws_size < gbytes) {
        k_fallback<<<2048, 256, 0, stream>>>(ps, support, weights, species, sids, out, n);
        return;
    }

    __bf16* gfrag = (__bf16*)d_ws;
    k_buildG<<<(NSPEC * 8 * 4 * 64 + 255) / 256, 256, 0, stream>>>(support, weights, gfrag);
    k_main<<<GRID, BLOCK, 0, stream>>>(ps, gfrag, species, sids, out, n);
}